// Round 5
// baseline (300.218 us; speedup 1.0000x reference)
//
#include <hip/hip_runtime.h>

#define QD 512
#define KD 64
#define NR 32    // rows per block
#define LDT 68   // o tile row stride in floats (64 + 4 pad)
#define LDU 72   // u tile row stride in shorts (64 + 8 pad)

typedef __attribute__((ext_vector_type(8))) short short8;
typedef __attribute__((ext_vector_type(4))) float f32x4;

static __device__ __forceinline__ unsigned short f2bf(float f) {
  unsigned u = __builtin_bit_cast(unsigned, f);
  u += 0x7FFFu + ((u >> 16) & 1u);   // round-to-nearest-even
  return (unsigned short)(u >> 16);
}
static __device__ __forceinline__ float bf2f(unsigned short s) {
  return __builtin_bit_cast(float, (unsigned)s << 16);
}
static __device__ __forceinline__ short8 pack8(f32x4 a, f32x4 b) {
  short8 r;
  r[0] = (short)f2bf(a[0]); r[1] = (short)f2bf(a[1]);
  r[2] = (short)f2bf(a[2]); r[3] = (short)f2bf(a[3]);
  r[4] = (short)f2bf(b[0]); r[5] = (short)f2bf(b[1]);
  r[6] = (short)f2bf(b[2]); r[7] = (short)f2bf(b[3]);
  return r;
}

// async global->LDS DMA, 16B/lane; LDS dest = wave-uniform base + lane*16.
static __device__ __forceinline__ void dma16(const void* g, void* l) {
  __builtin_amdgcn_global_load_lds(
      (const __attribute__((address_space(1))) void*)g,
      (__attribute__((address_space(3))) void*)l, 16, 0, 0);
}

// Prep: M^T[c][d] = sum_e w_q[e,d]*w_k[e,c]  (bf16), plus w_v cast to bf16.
__global__ __launch_bounds__(256) void prep_kernel(
    const float* __restrict__ w_q, const float* __restrict__ w_k,
    const float* __restrict__ w_v, unsigned short* __restrict__ mt,
    unsigned short* __restrict__ wvb) {
  const int tid = (int)(blockIdx.x * 256 + threadIdx.x);
  if (tid < QD * KD) {
    const int c = tid >> 9;      // 0..63
    const int d = tid & 511;     // 0..511
    float acc = 0.f;
#pragma unroll 8
    for (int e = 0; e < 64; ++e)
      acc = fmaf(w_q[e * QD + d], w_k[e * KD + c], acc);
    mt[c * QD + d] = f2bf(acc);
  } else {
    const int i = tid - QD * KD;
    if (i < KD * KD) wvb[i] = f2bf(w_v[i]);
  }
}

// ---------------- Phase A: t = query @ M  (t -> d_out as scratch) ----------
// Depth-4 DMA lookahead, 5-buffer ring, ONE barrier per chunk (with L+1
// buffers the fastest wave can only overwrite a buffer 5 chunks ahead, and
// the top-of-loop barrier blocks it before that). vmcnt counted: 6 in steady
// state (3 chunks x 2 instrs in flight), draining 4->2->0 in the epilogue.
// DMA source permutations give conflict-free-ish fragment reads with a
// LINEAR LDS dest (rule: swizzle source+read, never the dest):
//   q chunk buf  = [oct 0..7][row 0..31] 16B granules
//   mt chunk buf = [row 0..63][kgran 0..3] 16B granules
__global__ __launch_bounds__(256, 2) void gemm1_kernel(
    const float* __restrict__ query,
    const unsigned short* __restrict__ mt,
    float* __restrict__ tbuf) {
  __shared__ __align__(16) char qring[5 * 4096];   // 20480 B
  __shared__ __align__(16) char mring[5 * 4096];   // 20480 B

  const int tid  = (int)threadIdx.x;
  const int w    = tid >> 6;
  const int l    = tid & 63;
  const int m    = l & 15;
  const int quad = l >> 4;
  const long row0 = (long)blockIdx.x * NR;

  // per-thread DMA source addresses (permuted layouts, see header comment)
  const float* qsrc = query + (row0 + (tid & 31)) * QD + ((tid >> 5) << 2);
  const unsigned short* msrc = mt + (tid >> 2) * QD + ((tid & 3) << 3);

  // prologue: chunks 0..3 in flight (8 DMA instrs/wave -> statically counted)
#pragma unroll
  for (int c = 0; c < 4; ++c) {
    dma16(qsrc + c * 32, qring + c * 4096 + (w << 10));
    dma16(msrc + c * 32, mring + c * 4096 + (w << 10));
  }

  f32x4 acc[2];
  acc[0] = (f32x4){0.f, 0.f, 0.f, 0.f};
  acc[1] = (f32x4){0.f, 0.f, 0.f, 0.f};

#pragma unroll
  for (int c = 0; c < 16; ++c) {
    // wait: my chunk-c DMAs done <=> at most (newer chunks)*2 outstanding.
    // vmcnt drains oldest-first; stray vmem only makes this conservative.
    if (c <= 12)      { asm volatile("s_waitcnt vmcnt(6)" ::: "memory"); }
    else if (c == 13) { asm volatile("s_waitcnt vmcnt(4)" ::: "memory"); }
    else if (c == 14) { asm volatile("s_waitcnt vmcnt(2)" ::: "memory"); }
    else              { asm volatile("s_waitcnt vmcnt(0)" ::: "memory"); }
    __syncthreads();   // all waves' chunk-c DMA landed

    const char* qb = qring + (c % 5) * 4096;
    const char* bb = mring + (c % 5) * 4096;
    // B-frag: col = w*16+m, k-slice = quad*8..+7
    short8 bf = *(const short8*)(bb + ((w * 16 + m) << 6) + (quad << 4));
#pragma unroll
    for (int rt = 0; rt < 2; ++rt) {
      // A-frag: row = rt*16+m, k = quad*8+j  -> octs 2q, 2q+1 of [oct][row]
      f32x4 g0 = *(const f32x4*)(qb + (2 * quad) * 512 + ((rt * 16 + m) << 4));
      f32x4 g1 = *(const f32x4*)(qb + (2 * quad + 1) * 512 + ((rt * 16 + m) << 4));
      acc[rt] = __builtin_amdgcn_mfma_f32_16x16x32_bf16(pack8(g0, g1), bf,
                                                        acc[rt], 0, 0, 0);
    }
    if (c + 4 < 16) {   // refill ring: buf (c+4)%5 != any live buf c..c+3
      dma16(qsrc + (c + 4) * 32, qring + ((c + 4) % 5) * 4096 + (w << 10));
      dma16(msrc + (c + 4) * 32, mring + ((c + 4) % 5) * 4096 + (w << 10));
    }
  }

  // C layout: col = lane&15 (+16w), row = quad*4 + reg. Direct global write:
  // per store, 4 rows x 16 consecutive dwords -> 4 lines/instr. Fine.
#pragma unroll
  for (int rt = 0; rt < 2; ++rt)
#pragma unroll
    for (int r2 = 0; r2 < 4; ++r2)
      tbuf[(row0 + rt * 16 + quad * 4 + r2) * 64 + w * 16 + m] = acc[rt][r2];
}

// ---------------- Phase B: attention + GEMM2 + LN (in-place over t) --------
// No staging: t read coalesced (8 lanes/row x 32B), all 16 kv dwordx4 + 2 t
// loads issued as one batch per lane (launch_bounds(256,2) -> 256-VGPR budget
// so the allocator can keep them in flight; R1-R3 showed 64-80-VGPR budgets
// force load clustering). Each block reads ONLY rows it later writes.
__global__ __launch_bounds__(256, 2) void attn_kernel(
    const float* __restrict__ tbuf,
    const float* __restrict__ kv,
    const unsigned short* __restrict__ wvb,
    const float* __restrict__ gamma,
    const float* __restrict__ beta,
    float* __restrict__ out) {
  __shared__ __align__(16) float lds_t[NR * LDT];          // o tile, 8704 B
  __shared__ __align__(16) unsigned short lds_u[NR * LDU]; // u tile, 4608 B

  const int tid  = (int)threadIdx.x;
  const int w    = tid >> 6;
  const int l    = tid & 63;
  const int m    = l & 15;
  const int quad = l >> 4;
  const long row0 = (long)blockIdx.x * NR;

  const int rl = w * 8 + (l >> 3);   // row 0..31
  const int o8 = l & 7;              // dim segment
  const int db = o8 * 8;             // dim base
  const long brow = row0 + rl;

  // ---- batched loads: 2x t + 16x kv, all independent ----
  const float* tp = tbuf + brow * 64 + db;
  f32x4 tv0 = ((const f32x4*)tp)[0];
  f32x4 tv1 = ((const f32x4*)tp)[1];
  const float* kp = kv + (brow * 8) * 64 + db;
  f32x4 kf[16];
#pragma unroll
  for (int n = 0; n < 8; ++n) {
    kf[2 * n]     = ((const f32x4*)(kp + n * 64))[0];
    kf[2 * n + 1] = ((const f32x4*)(kp + n * 64))[1];
  }

  float s[8];
  short8 pk[8];
#pragma unroll
  for (int n = 0; n < 8; ++n) {
    f32x4 d = tv0 * kf[2 * n] + tv1 * kf[2 * n + 1];
    s[n] = d[0] + d[1] + d[2] + d[3];
    pk[n] = pack8(kf[2 * n], kf[2 * n + 1]);   // hold kv as bf16 for u pass
  }
#pragma unroll
  for (int n = 0; n < 8; ++n) {       // reduce partials across the 8 dim-lanes
    s[n] += __shfl_xor(s[n], 1, 64);
    s[n] += __shfl_xor(s[n], 2, 64);
    s[n] += __shfl_xor(s[n], 4, 64);
  }
  float mx = s[0];
#pragma unroll
  for (int n = 1; n < 8; ++n) mx = fmaxf(mx, s[n]);
  float ev[8];
  float esum = 0.f;
#pragma unroll
  for (int n = 0; n < 8; ++n) { ev[n] = __expf((s[n] - mx) * 0.125f); esum += ev[n]; }
  const float rinv = 1.0f / esum;

  f32x4 u0 = {0.f, 0.f, 0.f, 0.f}, u1 = u0;
#pragma unroll
  for (int n = 0; n < 8; ++n) {
    const float a = ev[n];
    short8 p = pk[n];
    u0 += a * (f32x4){bf2f((unsigned short)p[0]), bf2f((unsigned short)p[1]),
                      bf2f((unsigned short)p[2]), bf2f((unsigned short)p[3])};
    u1 += a * (f32x4){bf2f((unsigned short)p[4]), bf2f((unsigned short)p[5]),
                      bf2f((unsigned short)p[6]), bf2f((unsigned short)p[7])};
  }
  u0 *= rinv; u1 *= rinv;
  *(short8*)(lds_u + rl * LDU + db) = pack8(u0, u1);
  __syncthreads();

  // ---- GEMM2: o = u @ w_v^T (K=64, 2 MFMA k-steps) ----
  short8 wvf0 = *(const short8*)(wvb + (w * 16 + m) * 64 + quad * 8);
  short8 wvf1 = *(const short8*)(wvb + (w * 16 + m) * 64 + 32 + quad * 8);
  f32x4 o[2];
  o[0] = (f32x4){0.f, 0.f, 0.f, 0.f};
  o[1] = (f32x4){0.f, 0.f, 0.f, 0.f};
#pragma unroll
  for (int rt = 0; rt < 2; ++rt) {
    short8 a0 = *(const short8*)(lds_u + (rt * 16 + m) * LDU + quad * 8);
    o[rt] = __builtin_amdgcn_mfma_f32_16x16x32_bf16(a0, wvf0, o[rt], 0, 0, 0);
    short8 a1 = *(const short8*)(lds_u + (rt * 16 + m) * LDU + 32 + quad * 8);
    o[rt] = __builtin_amdgcn_mfma_f32_16x16x32_bf16(a1, wvf1, o[rt], 0, 0, 0);
  }
#pragma unroll
  for (int rt = 0; rt < 2; ++rt)
#pragma unroll
    for (int r2 = 0; r2 < 4; ++r2)
      lds_t[(rt * 16 + quad * 4 + r2) * LDT + w * 16 + m] = o[rt][r2];
  __syncthreads();

  // ---- LayerNorm over 64 dims (8 lanes per row), in-place store ----
  const float* op = lds_t + rl * LDT + db;
  f32x4 x0 = ((const f32x4*)op)[0];
  f32x4 x1 = ((const f32x4*)op)[1];
  f32x4 sv = x0 + x1;
  f32x4 sq = x0 * x0 + x1 * x1;
  float s1 = sv[0] + sv[1] + sv[2] + sv[3];
  float s2 = sq[0] + sq[1] + sq[2] + sq[3];
  s1 += __shfl_xor(s1, 1, 64); s1 += __shfl_xor(s1, 2, 64); s1 += __shfl_xor(s1, 4, 64);
  s2 += __shfl_xor(s2, 1, 64); s2 += __shfl_xor(s2, 2, 64); s2 += __shfl_xor(s2, 4, 64);
  const float mu   = s1 * 0.015625f;
  const float var  = s2 * 0.015625f - mu * mu;
  const float rstd = rsqrtf(var + 1e-5f);
  f32x4 g0 = ((const f32x4*)(gamma + db))[0], g1 = ((const f32x4*)(gamma + db))[1];
  f32x4 e0 = ((const f32x4*)(beta + db))[0],  e1 = ((const f32x4*)(beta + db))[1];
  float* dst = out + brow * 64 + db;
  ((f32x4*)dst)[0] = (x0 - mu) * rstd * g0 + e0;
  ((f32x4*)dst)[1] = (x1 - mu) * rstd * g1 + e1;
}

extern "C" void kernel_launch(void* const* d_in, const int* in_sizes, int n_in,
                              void* d_out, int out_size, void* d_ws, size_t ws_size,
                              hipStream_t stream) {
  const float* query = (const float*)d_in[0];
  const float* kv    = (const float*)d_in[1];
  const float* w_q   = (const float*)d_in[2];
  const float* w_k   = (const float*)d_in[3];
  const float* w_v   = (const float*)d_in[4];
  const float* gamma = (const float*)d_in[5];
  const float* beta  = (const float*)d_in[6];
  float* out = (float*)d_out;

  unsigned short* mt  = (unsigned short*)d_ws;   // 512*64 bf16
  unsigned short* wvb = mt + QD * KD;            // 64*64 bf16

  const int Bn = in_sizes[0] / QD;               // 65536

  prep_kernel<<<(QD * KD + KD * KD + 255) / 256, 256, 0, stream>>>(w_q, w_k, w_v, mt, wvb);
  // t parked in d_out (exactly 65536*64 fp32); attn_kernel overwrites in-place
  gemm1_kernel<<<Bn / NR, 256, 0, stream>>>(query, mt, out);
  attn_kernel<<<Bn / NR, 256, 0, stream>>>(out, kv, wvb, gamma, beta, out);
}